// Round 11
// baseline (311.111 us; speedup 1.0000x reference)
//
#include <hip/hip_runtime.h>
#include <cstdint>
#include <cstddef>

// ---------------- constants ----------------
#define NB      2048      // batch N
#define DIN     1024      // DIM_IN
#define DF      2048      // DIM_FEAT
#define DM      128       // DIM
#define NCLS    1000      // C
#define QQ      8         // Q
#define QC      8000      // Q*C
#define QCP     8064      // padded to 63*128
#define NLP     1024      // linW padded cols
#define CONW    3075      // 2047 + 4 + 1024
#define FSPLIT  16        // split-K factor for feat GEMM (klen=128 -> ONE_SHOT)
#define NBUCK   8192      // topk counting-sort buckets over [-1,1]

using float4v = __attribute__((ext_vector_type(4))) float;
using bf16x8  = __attribute__((ext_vector_type(8))) __bf16;

#define GLB_AS __attribute__((address_space(1)))
#define LDS_AS __attribute__((address_space(3)))

__device__ __forceinline__ unsigned short f2bf(float f) {
  unsigned int u = __float_as_uint(f);
  u += 0x7fffu + ((u >> 16) & 1u);   // round-to-nearest-even
  return (unsigned short)(u >> 16);
}
__device__ __forceinline__ float bf2f(unsigned short u) {
  return __uint_as_float(((unsigned int)u) << 16);
}

__device__ __forceinline__ bf16x8 ld_frag8(const unsigned short* p) {
  union { uint4 u; bf16x8 b; } cv;
  cv.u = *(const uint4*)p;
  return cv.b;
}

// async global->LDS, 16 bytes per lane; LDS dest = wave-uniform base + lane*16
__device__ __forceinline__ void gload_lds16(const unsigned short* g, unsigned short* l) {
  __builtin_amdgcn_global_load_lds((const GLB_AS unsigned int*)g,
                                   (LDS_AS unsigned int*)l, 16, 0, 0);
}

// topk histogram physical placement: rotate each thread's 8 chunks by thread id.
// logical chunk cch = b>>2 (owner t = cch>>3, j = cch&7) -> physical chunk
// (t*8) | ((j+t)&7). Scan reads chunk (j+t)&7 at STATIC register index j:
// banks balanced (group (j+t)&7) without runtime-indexed registers (r8 lesson).
__device__ __forceinline__ int hist_addr(int b) {
  int cch = b >> 2;
  int pch = (cch & ~7) | ((cch + (cch >> 3)) & 7);
  return (pch << 2) | (b & 3);
}

// ---------------- prep: fused transpose+convert (5 weights) + img conv ----------------
// Flattened exact 1D grid (11504 blocks) with per-mid base offsets — the old
// dim3(4096,6) grid launched 24576 blocks of which 13k early-returned.
// mids 0..4: src (K x N) f32 -> dst (Npad x K) bf16, zero pad rows >= N
//   write phase vectorized: 1 uint2 (4 bf16) store/thread instead of 4 scalar 2B
// mid 5: img f32 -> bf16 elementwise (vectorized x4)
struct TDescs {
  const float* src[6];
  unsigned short* dst[6];
  int K[6], N[6], nx[6], ky[6], base[6];
};
__global__ void prep_kernel(TDescs d) {
  const int bid = blockIdx.x;
  int mid = 0;
#pragma unroll
  for (int i = 1; i < 6; ++i) if (bid >= d.base[i]) mid = i;
  const int lb = bid - d.base[mid];
  const int tid = threadIdx.y * 32 + threadIdx.x;
  if (mid == 5) {
    const float* src = d.src[5];
    unsigned short* dst = d.dst[5];
    int base = lb * 1024 + tid * 4;
    float4 f = *(const float4*)(src + base);
    unsigned int lo = (unsigned int)f2bf(f.x) | ((unsigned int)f2bf(f.y) << 16);
    unsigned int hi = (unsigned int)f2bf(f.z) | ((unsigned int)f2bf(f.w) << 16);
    uint2 o; o.x = lo; o.y = hi;
    *(uint2*)(dst + base) = o;
    return;
  }
  const int nx = d.nx[mid];
  const int kb32 = lb / nx, nb32 = lb % nx;
  const float* src = d.src[mid];
  unsigned short* dst = d.dst[mid];
  const int K = d.K[mid], N = d.N[mid];
  const int nb = nb32 * 32, kb = kb32 * 32;
  __shared__ float tile[32][33];
  int tx = threadIdx.x, ty = threadIdx.y;
#pragma unroll
  for (int r = 0; r < 32; r += 8) {
    int k = kb + ty + r, n = nb + tx;
    tile[ty + r][tx] = (n < N) ? src[(size_t)k * N + n] : 0.f;
  }
  __syncthreads();
  // vectorized write: thread -> (n_local = tid>>3, k-quad = tid&7), one 8B store
  const int kq = tid & 7, nl = tid >> 3;
  unsigned int lo = (unsigned int)f2bf(tile[kq * 4 + 0][nl]) |
                    ((unsigned int)f2bf(tile[kq * 4 + 1][nl]) << 16);
  unsigned int hi = (unsigned int)f2bf(tile[kq * 4 + 2][nl]) |
                    ((unsigned int)f2bf(tile[kq * 4 + 3][nl]) << 16);
  uint2 o; o.x = lo; o.y = hi;
  *(uint2*)(dst + (size_t)(nb + nl) * K + kb + kq * 4) = o;
}

// ---------------- GEMM: C[m][n] = sum_k A[m][k]*Bt[n][k] (+bias[n]) ----------------
// 128x128 tile, 4 waves 2x2, acc 4x4, BK=64, double-buffered global_load_lds.
// LDS XOR-swizzle (16B-unit ^ (row&7)) on BOTH pre-swizzled global source and
// ds_read address. Linear blockIdx (r5: chunked XCD swizzle = +14.5MB fetch, no win).
// NO device fences in epilogue (r6: __threadfence in 256 blocks = +30us L2-flush cost).
// ONE_SHOT (klen==128 only): issue both 64-wide stages up front, single barrier,
// no further syncs — kills the degenerate NKT=2 double-drain (sim + feat GEMMs).
// OUT_MODE: 0 = f32 store, 1 = bf16 store,
//           3 = fused h(bf16,+BN stats, n0<DF) / logit(f32->Cout2, n0>=DF)
//           4 = fused sim_q(bf16, n0<QCP) / sim_b off-diag scatter(f32->Cout2, n0>=QCP)
// blockIdx.z = split-K slice (k range [z*klen, +klen), output offset z*NB*ldc)
template<int OUT_MODE, bool HAS_BIAS, bool BN_STATS, bool ONE_SHOT>
__global__ __launch_bounds__(256) void gemm_bt_kernel(
    const unsigned short* __restrict__ A,
    const unsigned short* __restrict__ Bt,
    const float* __restrict__ bias,
    const float* __restrict__ bias2,
    void* __restrict__ Cout,
    void* __restrict__ Cout2,
    int lda, int klen, int ldc, int n_store,
    float* __restrict__ ps, float* __restrict__ ps2)
{
  __shared__ __align__(16) unsigned short As[2][128][64];   // 32 KB
  __shared__ __align__(16) unsigned short Bs[2][128][64];   // 32 KB
  const int m0 = blockIdx.y * 128, n0 = blockIdx.x * 128;
  const int z  = blockIdx.z;
  const int tid = threadIdx.x;
  const int lane = tid & 63, w = tid >> 6;
  const int wm = (w >> 1) * 64, wn = (w & 1) * 64;
  const int lrow = lane & 15, lq = lane >> 4;
  const int r7 = lrow & 7;                 // read-side swizzle key

  const unsigned short* Abase = A  + (size_t)m0 * lda + z * klen;
  const unsigned short* Bbase = Bt + (size_t)n0 * lda + z * klen;

  // 128x64 tile = 1024 chunks of 8 bf16; 4 chunks/thread/matrix.
  // chunk c: row = c>>3, slot (c&7); source 16B-unit = (c&7) ^ (row&7)  (pre-swizzle)
  int cc[4]; size_t goff[4];
#pragma unroll
  for (int q = 0; q < 4; ++q) {
    int c = tid + 256 * q;
    int row = c >> 3;
    int ucol = (c & 7) ^ (row & 7);
    cc[q] = c;
    goff[q] = (size_t)row * lda + ucol * 8;
  }

  float4v acc[4][4];
#pragma unroll
  for (int i = 0; i < 4; ++i)
#pragma unroll
    for (int j = 0; j < 4; ++j)
      acc[i][j] = (float4v){0.f, 0.f, 0.f, 0.f};

  auto stage = [&](int buf, int k0) {
#pragma unroll
    for (int q = 0; q < 4; ++q)
      gload_lds16(Abase + goff[q] + k0, &As[buf][0][0] + cc[q] * 8);
#pragma unroll
    for (int q = 0; q < 4; ++q)
      gload_lds16(Bbase + goff[q] + k0, &Bs[buf][0][0] + cc[q] * 8);
  };
  auto compute = [&](int b) {
#pragma unroll
    for (int kk = 0; kk < 2; ++kk) {
      bf16x8 af[4], bfr[4];
#pragma unroll
      for (int i = 0; i < 4; ++i)
        af[i]  = ld_frag8(&As[b][wm + i * 16 + lrow][(((kk << 2) + lq) ^ r7) << 3]);
#pragma unroll
      for (int j = 0; j < 4; ++j)
        bfr[j] = ld_frag8(&Bs[b][wn + j * 16 + lrow][(((kk << 2) + lq) ^ r7) << 3]);
#pragma unroll
      for (int i = 0; i < 4; ++i)
#pragma unroll
        for (int j = 0; j < 4; ++j)
          acc[i][j] = __builtin_amdgcn_mfma_f32_16x16x32_bf16(af[i], bfr[j], acc[i][j], 0, 0, 0);
    }
  };

  if constexpr (ONE_SHOT) {
    // klen == 128: both stages in flight, one barrier, no further syncs
    stage(0, 0);
    stage(1, 64);
    __syncthreads();
    compute(0);
    compute(1);
  } else {
    const int NKT = klen / 64;
    stage(0, 0);
    for (int t = 0; t < NKT; ++t) {
      __syncthreads();                     // drains this iter's buffer (vmcnt) + prev compute (lgkm)
      if (t + 1 < NKT) stage((t + 1) & 1, (t + 1) * 64);
      compute(t & 1);
    }
  }

  // block-uniform secondary-output test (DF and QCP are multiples of 128)
  const bool is2nd = (OUT_MODE == 3 && n0 >= DF) || (OUT_MODE == 4 && n0 >= QCP);
  const bool do_bn = BN_STATS && !is2nd;

  float* cs  = (float*)&As[0][0][0];
  float* cs2 = cs + 128;
  if (do_bn) {
    __syncthreads();
    if (tid < 256) cs[tid] = 0.f;          // zero cs[0..127], cs2[0..127]
    __syncthreads();
  }

  float*          outf  = (float*)Cout          + (size_t)z * NB * ldc;
  unsigned short* outh  = (unsigned short*)Cout + (size_t)z * NB * ldc;
  float*          outf2 = (float*)Cout2;

#pragma unroll
  for (int j = 0; j < 4; ++j) {
    int gcol = n0 + wn + j * 16 + lrow;
    float bv = 0.f;
    if (OUT_MODE == 3) {
      if (!is2nd) bv = bias[gcol];
      else if (gcol - DF < NCLS) bv = bias2[gcol - DF];
    } else if (HAS_BIAS && gcol < n_store) bv = bias[gcol];
    float sj = 0.f, s2j = 0.f;
#pragma unroll
    for (int i = 0; i < 4; ++i) {
#pragma unroll
      for (int r = 0; r < 4; ++r) {
        int grow = m0 + wm + i * 16 + lq * 4 + r;  // C/D: col=lane&15, row=(lane>>4)*4+r
        float val = acc[i][j][r] + bv;
        if (do_bn) { sj += val; s2j += val * val; }
        if (OUT_MODE == 0) {
          if (gcol < n_store) outf[(size_t)grow * ldc + gcol] = val;
        } else if (OUT_MODE == 1) {
          if (gcol < n_store) outh[(size_t)grow * ldc + gcol] = f2bf(val);
        } else if (OUT_MODE == 3) {
          if (!is2nd) outh[(size_t)grow * DF + gcol] = f2bf(val);
          else if (gcol - DF < NCLS) outf2[(size_t)grow * NCLS + (gcol - DF)] = val;
        } else if (OUT_MODE == 4) {
          if (!is2nd) { if (gcol < QC) outh[(size_t)grow * QC + gcol] = f2bf(val); }
          else {
            int gc2 = gcol - QCP;
            if (gc2 != grow) outf2[(size_t)grow * CONW + gc2 - (gc2 > grow)] = val;
          }
        }
      }
    }
    if (do_bn) {
      atomicAdd(&cs [wn + j * 16 + lrow], sj);
      atomicAdd(&cs2[wn + j * 16 + lrow], s2j);
    }
  }
  if (do_bn) {
    __syncthreads();
    if (tid < 128) {
      ps [(size_t)blockIdx.y * DF + n0 + tid] = cs[tid];
      ps2[(size_t)blockIdx.y * DF + n0 + tid] = cs2[tid];
    }
  }
}

// ---------------- BatchNorm finish ----------------
__global__ void bn_finish_kernel(const float* __restrict__ ps, const float* __restrict__ ps2,
                                 const float* __restrict__ gamma, const float* __restrict__ beta,
                                 float* __restrict__ scale, float* __restrict__ bias) {
  int j = blockIdx.x * 256 + threadIdx.x;
  float s = 0.f, s2 = 0.f;
  for (int b = 0; b < 16; ++b) { s += ps[b * DF + j]; s2 += ps2[b * DF + j]; }
  float mu  = s  * (1.f / NB);
  float var = s2 * (1.f / NB) - mu * mu;
  float sc = gamma[j] * rsqrtf(var + 1e-5f);
  scale[j] = sc;
  bias[j]  = beta[j] - mu * sc;
}

// bf16 in -> scale/shift/relu -> bf16 out, 8 elems/thread
__global__ void bn_apply_kernel(const unsigned short* __restrict__ h, const float* __restrict__ scale,
                                const float* __restrict__ bias, unsigned short* __restrict__ hb) {
  int base = (blockIdx.x * 256 + threadIdx.x) * 8;
  int j = base & (DF - 1);
  uint4 u = *(const uint4*)(h + base);
  unsigned int uu[4] = {u.x, u.y, u.z, u.w};
  unsigned int rr[4];
#pragma unroll
  for (int e = 0; e < 4; ++e) {
    int col = j + 2 * e;
    float lo = bf2f((unsigned short)(uu[e] & 0xffffu));
    float hi = bf2f((unsigned short)(uu[e] >> 16));
    lo = fmaxf(lo * scale[col] + bias[col], 0.f);
    hi = fmaxf(hi * scale[col + 1] + bias[col + 1], 0.f);
    rr[e] = (unsigned int)f2bf(lo) | ((unsigned int)f2bf(hi) << 16);
  }
  uint4 o; o.x = rr[0]; o.y = rr[1]; o.z = rr[2]; o.w = rr[3];
  *(uint4*)(hb + base) = o;
}

// ---------------- feat: split-K reduce + bias + row-normalize ----------------
__global__ void feat_reduce_norm_kernel(const float* __restrict__ part, const float* __restrict__ b2,
                                        float* __restrict__ fo, unsigned short* __restrict__ fb) {
  int row = blockIdx.x, t = threadIdx.x;   // 64 threads
  float v0 = b2[t], v1 = b2[64 + t];
#pragma unroll
  for (int s = 0; s < FSPLIT; ++s) {
    const float* p = part + (size_t)s * NB * DM + (size_t)row * DM;
    v0 += p[t]; v1 += p[64 + t];
  }
  float ss = v0 * v0 + v1 * v1;
#pragma unroll
  for (int o = 32; o > 0; o >>= 1) ss += __shfl_xor(ss, o);
  float inv = rsqrtf(ss);
  v0 *= inv; v1 *= inv;
  fo[row * DM + t] = v0;       fo[row * DM + 64 + t] = v1;
  fb[row * DM + t] = f2bf(v0); fb[row * DM + 64 + t] = f2bf(v1);
}

// ---------------- top-k (counting sort) + fused labels_con ----------------
// Histogram stored ROTATED-per-thread (hist_addr): scan reads chunk (j+t)&7 at
// static register index j -> banks balanced AND no runtime register indexing
// (r8: runtime cnt[4r] went to scratch, +63us; r7: unrotated = 7.46M conflicts).
__global__ __launch_bounds__(256) void topk_kernel(const unsigned short* __restrict__ sim_qb,
                                                   const int* __restrict__ labels,
                                                   float* __restrict__ out_simcon,
                                                   float* __restrict__ out_labcon) {
  __shared__ unsigned int hist[NBUCK];    // 32 KB; becomes offsets after scan
  __shared__ float sbuf[1024];
  __shared__ unsigned int wtot[4];
  __shared__ int s_tb;

  const int row = blockIdx.x;
  const int c = labels[row];
  const int t = threadIdx.x;
  const int w = t >> 6, lane = t & 63;

  uint4* h4 = (uint4*)hist;
  uint4 z4; z4.x = z4.y = z4.z = z4.w = 0u;
#pragma unroll
  for (int i = 0; i < 8; ++i) h4[t + 256 * i] = z4;

  float vals[32];
  float pvals[QQ];
  const unsigned short* rp = sim_qb + (size_t)row * QC;
#pragma unroll
  for (int j = 0; j < 4; ++j) {
    const int cls = j * 256 + t;
    uint4 u4 = *(const uint4*)(rp + j * 2048 + t * 8);
    const unsigned int uu[4] = {u4.x, u4.y, u4.z, u4.w};
    const bool masked = (cls >= NCLS) || (cls == c);
#pragma unroll
    for (int e = 0; e < 4; ++e) {
      float lo = bf2f((unsigned short)(uu[e] & 0xffffu));
      float hi = bf2f((unsigned short)(uu[e] >> 16));
      if (cls == c) { pvals[2 * e] = lo; pvals[2 * e + 1] = hi; }
      vals[j * 8 + 2 * e]     = masked ? -4.f : lo;
      vals[j * 8 + 2 * e + 1] = masked ? -4.f : hi;
    }
  }
  __syncthreads();

#pragma unroll
  for (int i = 0; i < 32; ++i) {
    float v = vals[i];
    if (v > -3.f) {
      int b = (int)((v + 1.0f) * 4096.0f);
      b = min(max(b, 0), NBUCK - 1);
      atomicAdd(&hist[hist_addr(b)], 1u);
    }
  }
  __syncthreads();

  unsigned int cnt[32];
#pragma unroll
  for (int j = 0; j < 8; ++j) {
    uint4 u = h4[t * 8 + ((j + t) & 7)];   // rotated address, STATIC register index
    cnt[4 * j] = u.x; cnt[4 * j + 1] = u.y; cnt[4 * j + 2] = u.z; cnt[4 * j + 3] = u.w;
  }
  unsigned int chunktot = 0;
#pragma unroll
  for (int i = 0; i < 32; ++i) chunktot += cnt[i];

  unsigned int s = chunktot;
#pragma unroll
  for (int off = 1; off < 64; off <<= 1) {
    unsigned int v = __shfl_down(s, off);
    if (lane + off < 64) s += v;
  }
  if (lane == 0) wtot[w] = s;
  __syncthreads();
  unsigned int wsfx = 0;
#pragma unroll
  for (int ww = 0; ww < 4; ++ww) if (ww > w) wsfx += wtot[ww];
  unsigned int S = wsfx + s - chunktot;

  unsigned int ofsv[32];
#pragma unroll
  for (int i = 31; i >= 0; --i) {
    unsigned int cb = cnt[i];
    ofsv[i] = S;
    unsigned int Sincl = S + cb;
    if (S < 1024u && Sincl >= 1024u) s_tb = t * 32 + i;
    S = Sincl;
  }
#pragma unroll
  for (int j = 0; j < 8; ++j) {
    uint4 u;
    u.x = ofsv[4 * j]; u.y = ofsv[4 * j + 1]; u.z = ofsv[4 * j + 2]; u.w = ofsv[4 * j + 3];
    h4[t * 8 + ((j + t) & 7)] = u;         // rotated address, STATIC register index
  }
  __syncthreads();

  const int tb = s_tb;
#pragma unroll
  for (int i = 0; i < 32; ++i) {
    float v = vals[i];
    if (v > -3.f) {
      int b = (int)((v + 1.0f) * 4096.0f);
      b = min(max(b, 0), NBUCK - 1);
      if (b >= tb) {
        unsigned int p = atomicAdd(&hist[hist_addr(b)], 1u);
        if (p < 1024u) sbuf[p] = v;
      }
    }
  }
  __syncthreads();

  float* orow = out_simcon + (size_t)row * CONW;
  for (int idx = t; idx < 1024; idx += 256) orow[2051 + idx] = sbuf[idx];
  if (t == (c & 255) && (c >> 8) < 4 && (c >> 8) * 256 + t == c) {
    for (int a2 = 1; a2 < QQ; ++a2) {
      float key = pvals[a2]; int b2 = a2 - 1;
      while (b2 >= 0 && pvals[b2] > key) { pvals[b2 + 1] = pvals[b2]; --b2; }
      pvals[b2 + 1] = key;
    }
#pragma unroll
    for (int s2 = 0; s2 < 4; ++s2) orow[2047 + s2] = pvals[s2];
  }

  // fused labels_con (same grid, independent of the topk output above)
  float* lrow = out_labcon + (size_t)row * CONW;
  for (int j = t; j < CONW; j += 256) {
    float v;
    if (j < NB - 1)      v = (labels[j + (j >= row)] == c) ? 1.f : 0.f;
    else if (j < NB + 3) v = 1.f;    // 2047..2050 -> pos ones
    else                 v = 0.f;    // negs
    lrow[j] = v;
  }
}

// ---------------- queue update: fused scan (wave 0) + gather-write (all threads) ----------------
__global__ void queue_update_kernel(const int* __restrict__ labels, const int* __restrict__ qptr_in,
                                    const float* __restrict__ feat, const float* __restrict__ qin,
                                    float* __restrict__ qout, float* __restrict__ qptr_out) {
  __shared__ int wloc[QQ];
  const int c = blockIdx.x;
  const int t = threadIdx.x;         // 256 threads
  const int lane = t & 63;
  if (t < QQ) wloc[t] = -1;
  __syncthreads();
  const int p0 = qptr_in[c];
  if (t < 64) {                      // wave 0 only: ballot scan over first NB/2 labels
    int cnt = 0;
#pragma unroll
    for (int it = 0; it < (NB / 2) / 64; ++it) {
      int i = it * 64 + lane;
      bool pred = (labels[i] == c);
      unsigned long long mask = __ballot(pred);
      if (pred) {
        int rank = __popcll(mask & ((1ull << lane) - 1ull));
        int slot = (p0 + cnt + rank) & (QQ - 1);
        atomicMax(&wloc[slot], i);
      }
      cnt += __popcll(mask);
    }
    if (lane == 0) qptr_out[c] = (float)((p0 + cnt) & (QQ - 1));
  }
  __syncthreads();
  // write the 8 columns owned by class c: cols c*8 .. c*8+7, all 128 d-rows.
  // thread t -> d = t>>1, half = t&1 (4 consecutive cols as float4)
  const int d = t >> 1, half = t & 1;
  const size_t rowbase = (size_t)d * QC + c * QQ + half * 4;
  float4 v = *(const float4*)(qin + rowbase);
  float vv[4] = {v.x, v.y, v.z, v.w};
#pragma unroll
  for (int s = 0; s < 4; ++s) {
    int wsrc = wloc[half * 4 + s];
    if (wsrc >= 0) vv[s] = feat[(size_t)wsrc * DM + d];
  }
  float4 o; o.x = vv[0]; o.y = vv[1]; o.z = vv[2]; o.w = vv[3];
  *(float4*)(qout + rowbase) = o;
}

// ---------------- launcher ----------------
extern "C" void kernel_launch(void* const* d_in, const int* in_sizes, int n_in,
                              void* d_out, int out_size, void* d_ws, size_t ws_size,
                              hipStream_t stream) {
  const float* img     = (const float*)d_in[0];
  const int*   labels  = (const int*)  d_in[1];
  const float* queue_l = (const float*)d_in[2];
  const int*   queue_p = (const int*)  d_in[3];
  // d_in[4] pos_index, d_in[5] neg_index: analytic, unused
  const float* enc_W   = (const float*)d_in[6];
  const float* enc_b   = (const float*)d_in[7];
  const float* W1      = (const float*)d_in[8];
  const float* b1      = (const float*)d_in[9];
  const float* gamma   = (const float*)d_in[10];
  const float* beta    = (const float*)d_in[11];
  const float* W2      = (const float*)d_in[12];
  const float* b2      = (const float*)d_in[13];
  const float* linW    = (const float*)d_in[14];
  const float* linb    = (const float*)d_in[15];

  float* out        = (float*)d_out;
  float* out_simcon = out;
  float* out_labcon = out + (size_t)NB * CONW;
  float* out_logit  = out + (size_t)2 * NB * CONW;
  float* out_qlist  = out_logit + (size_t)NB * NCLS;
  float* out_qptr   = out_qlist + (size_t)DM * QC;

  char* wsp = (char*)d_ws;
  size_t off = 0;
  auto alloc = [&](size_t bytes) -> void* {
    void* p = wsp + off;
    off += (bytes + 255) & ~(size_t)255;
    return p;
  };
  unsigned short* img_bf  = (unsigned short*)alloc((size_t)NB * DIN * 2);
  unsigned short* encWt   = (unsigned short*)alloc((size_t)DF * DIN * 2);   // 2048 x 1024
  // W1t + linWt contiguous (both sizes multiple of 256B) -> fused h+logit B
  unsigned short* W1t     = (unsigned short*)alloc((size_t)DF * DF * 2);    // 2048 x 2048
  unsigned short* linWt   = (unsigned short*)alloc((size_t)NLP * DF * 2);   // 1024 x 2048
  unsigned short* W2t     = (unsigned short*)alloc((size_t)DM * DF * 2);    // 128 x 2048
  // qlt + feat_bf contiguous (qlt size multiple of 256B) -> fused sim B
  unsigned short* qlt     = (unsigned short*)alloc((size_t)QCP * DM * 2);   // 8064 x 128
  unsigned short* feat_bf = (unsigned short*)alloc((size_t)NB * DM * 2);    // 2048 x 128
  unsigned short* mid_bf  = (unsigned short*)alloc((size_t)NB * DF * 2);
  unsigned short* h_pbf   = (unsigned short*)alloc((size_t)NB * DF * 2);    // pre-BN h, bf16
  unsigned short* h_bf    = (unsigned short*)alloc((size_t)NB * DF * 2);    // post-BN h, bf16
  float*          part_s  = (float*)alloc((size_t)16 * DF * 4);
  float*          part_s2 = (float*)alloc((size_t)16 * DF * 4);
  float*          bn_sc   = (float*)alloc((size_t)DF * 4);
  float*          bn_bi   = (float*)alloc((size_t)DF * 4);
  float*          feat_part=(float*)alloc((size_t)FSPLIT * NB * DM * 4);    // 16 MB
  float*          feat_f  = (float*)alloc((size_t)NB * DM * 4);
  unsigned short* sim_qb  = (unsigned short*)alloc((size_t)NB * QC * 2 + 512); // bf16 + read pad

  dim3 blk256(256);
  dim3 tblk(32, 8);

  // --- prep: img conv + transpose of all 5 weight matrices (exact flattened grid) ---
  TDescs td;
  td.src[0] = enc_W;  td.dst[0] = encWt; td.K[0] = DIN; td.N[0] = DF;   td.nx[0] = DF / 32;   td.ky[0] = DIN / 32;
  td.src[1] = W1;     td.dst[1] = W1t;   td.K[1] = DF;  td.N[1] = DF;   td.nx[1] = DF / 32;   td.ky[1] = DF / 32;
  td.src[2] = W2;     td.dst[2] = W2t;   td.K[2] = DF;  td.N[2] = DM;   td.nx[2] = DM / 32;   td.ky[2] = DF / 32;
  td.src[3] = linW;   td.dst[3] = linWt; td.K[3] = DF;  td.N[3] = NCLS; td.nx[3] = NLP / 32;  td.ky[3] = DF / 32;
  td.src[4] = queue_l;td.dst[4] = qlt;   td.K[4] = DM;  td.N[4] = QC;   td.nx[4] = QCP / 32;  td.ky[4] = DM / 32;
  td.src[5] = img;    td.dst[5] = img_bf;td.K[5] = 0;   td.N[5] = 0;    td.nx[5] = 1;         td.ky[5] = 0;
  int nblk = 0;
  for (int i = 0; i < 6; ++i) {
    td.base[i] = nblk;
    nblk += (i == 5) ? (NB * DIN) / 1024 : td.nx[i] * td.ky[i];
  }
  prep_kernel<<<dim3(nblk), tblk, 0, stream>>>(td);

  // --- mid = img @ enc_W + enc_b  (bf16 out) ---
  gemm_bt_kernel<1, true, false, false><<<dim3(DF / 128, NB / 128), blk256, 0, stream>>>(
      img_bf, encWt, enc_b, nullptr, mid_bf, nullptr, DIN, DIN, DF, DF, nullptr, nullptr);

  // --- fused: h_pbf = mid @ W1 + b1 (bf16 + BN stats) ; logit = mid @ lin_W + lin_b ---
  gemm_bt_kernel<3, true, true, false><<<dim3((DF + NLP) / 128, NB / 128), blk256, 0, stream>>>(
      mid_bf, W1t, b1, linb, h_pbf, out_logit, DF, DF, DF, DF, part_s, part_s2);

  // --- batchnorm finish + apply -> h_bf ---
  bn_finish_kernel<<<dim3(DF / 256), blk256, 0, stream>>>(part_s, part_s2, gamma, beta, bn_sc, bn_bi);
  bn_apply_kernel<<<dim3((NB * DF) / 2048), blk256, 0, stream>>>(h_pbf, bn_sc, bn_bi, h_bf);

  // --- feat partials = h @ W2 (split-K x16, klen=128 -> ONE_SHOT, 256 blocks) ---
  gemm_bt_kernel<0, false, false, true><<<dim3(DM / 128, NB / 128, FSPLIT), blk256, 0, stream>>>(
      h_bf, W2t, nullptr, nullptr, feat_part, nullptr, DF, DF / FSPLIT, DM, DM, nullptr, nullptr);

  // --- feat reduce + bias + normalize ---
  feat_reduce_norm_kernel<<<dim3(NB), dim3(64), 0, stream>>>(feat_part, b2, feat_f, feat_bf);

  // --- fused: sim_q = feat @ queue (bf16) ; sim_b = feat @ feat^T off-diag into sim_con ---
  // K=128 -> ONE_SHOT single-barrier variant
  gemm_bt_kernel<4, false, false, true><<<dim3((QCP + NB) / 128, NB / 128), blk256, 0, stream>>>(
      feat_bf, qlt, nullptr, nullptr, sim_qb, out_simcon, DM, DM, QC, QC, nullptr, nullptr);

  // --- top-k / pos-sel into sim_con + fused labels_con ---
  topk_kernel<<<dim3(NB), blk256, 0, stream>>>(sim_qb, labels, out_simcon, out_labcon);

  // --- queue update (fused scan + write) ---
  queue_update_kernel<<<dim3(NCLS), blk256, 0, stream>>>(labels, queue_p, feat_f, queue_l,
                                                         out_qlist, out_qptr);
}

// Round 12
// 304.940 us; speedup vs baseline: 1.0202x; 1.0202x over previous
//
#include <hip/hip_runtime.h>
#include <cstdint>
#include <cstddef>

// ---------------- constants ----------------
#define NB      2048      // batch N
#define DIN     1024      // DIM_IN
#define DF      2048      // DIM_FEAT
#define DM      128       // DIM
#define NCLS    1000      // C
#define QQ      8         // Q
#define QC      8000      // Q*C
#define QCP     8064      // padded to 63*128
#define NLP     1024      // linW padded cols
#define CONW    3075      // 2047 + 4 + 1024
#define FSPLIT  8         // split-K factor for feat GEMM
#define NBUCK   8192      // topk counting-sort buckets over [-1,1]

using float4v = __attribute__((ext_vector_type(4))) float;
using bf16x8  = __attribute__((ext_vector_type(8))) __bf16;

#define GLB_AS __attribute__((address_space(1)))
#define LDS_AS __attribute__((address_space(3)))

__device__ __forceinline__ unsigned short f2bf(float f) {
  unsigned int u = __float_as_uint(f);
  u += 0x7fffu + ((u >> 16) & 1u);   // round-to-nearest-even
  return (unsigned short)(u >> 16);
}
__device__ __forceinline__ float bf2f(unsigned short u) {
  return __uint_as_float(((unsigned int)u) << 16);
}

__device__ __forceinline__ bf16x8 ld_frag8(const unsigned short* p) {
  union { uint4 u; bf16x8 b; } cv;
  cv.u = *(const uint4*)p;
  return cv.b;
}

// async global->LDS, 16 bytes per lane; LDS dest = wave-uniform base + lane*16
__device__ __forceinline__ void gload_lds16(const unsigned short* g, unsigned short* l) {
  __builtin_amdgcn_global_load_lds((const GLB_AS unsigned int*)g,
                                   (LDS_AS unsigned int*)l, 16, 0, 0);
}

// topk histogram physical placement: rotate each thread's 8 chunks by thread id.
// logical chunk cch = b>>2 (owner t = cch>>3, j = cch&7) -> physical chunk
// (t*8) | ((j+t)&7). Scan reads chunk (j+t)&7 at STATIC register index j:
// banks balanced (group (j+t)&7) without runtime-indexed registers (r8 lesson).
__device__ __forceinline__ int hist_addr(int b) {
  int cch = b >> 2;
  int pch = (cch & ~7) | ((cch + (cch >> 3)) & 7);
  return (pch << 2) | (b & 3);
}

// ---------------- prep: fused transpose+convert (5 weights) + img conv ----------------
// mids 0..4: src (K x N) f32 -> dst (Npad x K) bf16, zero pad rows >= N
//   write phase vectorized: 1 uint2 (4 bf16) store/thread instead of 4 scalar 2B
// mid 5: img f32 -> bf16 elementwise (vectorized x4)
struct TDescs {
  const float* src[6];
  unsigned short* dst[6];
  int K[6], N[6], nx[6], ky[6];
};
__global__ void prep_kernel(TDescs d) {
  const int mid = blockIdx.y;
  const int tid = threadIdx.y * 32 + threadIdx.x;
  if (mid == 5) {
    if (blockIdx.x < (NB * DIN) / 1024) {
      const float* src = d.src[5];
      unsigned short* dst = d.dst[5];
      int base = blockIdx.x * 1024 + tid * 4;
      float4 f = *(const float4*)(src + base);
      unsigned int lo = (unsigned int)f2bf(f.x) | ((unsigned int)f2bf(f.y) << 16);
      unsigned int hi = (unsigned int)f2bf(f.z) | ((unsigned int)f2bf(f.w) << 16);
      uint2 o; o.x = lo; o.y = hi;
      *(uint2*)(dst + base) = o;
    }
    return;
  }
  const int nx = d.nx[mid];
  const int kb32 = blockIdx.x / nx, nb32 = blockIdx.x % nx;
  if (kb32 >= d.ky[mid]) return;
  const float* src = d.src[mid];
  unsigned short* dst = d.dst[mid];
  const int K = d.K[mid], N = d.N[mid];
  const int nb = nb32 * 32, kb = kb32 * 32;
  __shared__ float tile[32][33];
  int tx = threadIdx.x, ty = threadIdx.y;
#pragma unroll
  for (int r = 0; r < 32; r += 8) {
    int k = kb + ty + r, n = nb + tx;
    tile[ty + r][tx] = (n < N) ? src[(size_t)k * N + n] : 0.f;
  }
  __syncthreads();
  // vectorized write: thread -> (n_local = tid>>3, k-quad = tid&7), one 8B store
  const int kq = tid & 7, nl = tid >> 3;
  unsigned int lo = (unsigned int)f2bf(tile[kq * 4 + 0][nl]) |
                    ((unsigned int)f2bf(tile[kq * 4 + 1][nl]) << 16);
  unsigned int hi = (unsigned int)f2bf(tile[kq * 4 + 2][nl]) |
                    ((unsigned int)f2bf(tile[kq * 4 + 3][nl]) << 16);
  uint2 o; o.x = lo; o.y = hi;
  *(uint2*)(dst + (size_t)(nb + nl) * K + kb + kq * 4) = o;
}

// ---------------- GEMM: C[m][n] = sum_k A[m][k]*Bt[n][k] (+bias[n]) ----------------
// 128x128 tile, 4 waves 2x2, acc 4x4, BK=64, double-buffered global_load_lds.
// LDS XOR-swizzle (16B-unit ^ (row&7)) on BOTH pre-swizzled global source and
// ds_read address. Linear blockIdx (r5: chunked XCD swizzle = +14.5MB fetch, no win).
// NO device fences in epilogue (r6: __threadfence in 256 blocks = +30us L2-flush cost).
// ONE_SHOT (klen==128 only): issue both 64-wide stages up front, single barrier,
// no further syncs — kills the degenerate NKT=2 double-drain (sim GEMM).
// Instantiation set {1f,3f,0f,4t} is the r10-measured best — do NOT change it
// casually: r11 swapped 0f->0t and the co-compiled h+logit (3f) dispatch went
// 48->67us at identical counters (rule #19 codegen perturbation / env noise).
// OUT_MODE: 0 = f32 store, 1 = bf16 store,
//           3 = fused h(bf16,+BN stats, n0<DF) / logit(f32->Cout2, n0>=DF)
//           4 = fused sim_q(bf16, n0<QCP) / sim_b off-diag scatter(f32->Cout2, n0>=QCP)
// blockIdx.z = split-K slice (k range [z*klen, +klen), output offset z*NB*ldc)
template<int OUT_MODE, bool HAS_BIAS, bool BN_STATS, bool ONE_SHOT>
__global__ __launch_bounds__(256) void gemm_bt_kernel(
    const unsigned short* __restrict__ A,
    const unsigned short* __restrict__ Bt,
    const float* __restrict__ bias,
    const float* __restrict__ bias2,
    void* __restrict__ Cout,
    void* __restrict__ Cout2,
    int lda, int klen, int ldc, int n_store,
    float* __restrict__ ps, float* __restrict__ ps2)
{
  __shared__ __align__(16) unsigned short As[2][128][64];   // 32 KB
  __shared__ __align__(16) unsigned short Bs[2][128][64];   // 32 KB
  const int m0 = blockIdx.y * 128, n0 = blockIdx.x * 128;
  const int z  = blockIdx.z;
  const int tid = threadIdx.x;
  const int lane = tid & 63, w = tid >> 6;
  const int wm = (w >> 1) * 64, wn = (w & 1) * 64;
  const int lrow = lane & 15, lq = lane >> 4;
  const int r7 = lrow & 7;                 // read-side swizzle key

  const unsigned short* Abase = A  + (size_t)m0 * lda + z * klen;
  const unsigned short* Bbase = Bt + (size_t)n0 * lda + z * klen;

  // 128x64 tile = 1024 chunks of 8 bf16; 4 chunks/thread/matrix.
  // chunk c: row = c>>3, slot (c&7); source 16B-unit = (c&7) ^ (row&7)  (pre-swizzle)
  int cc[4]; size_t goff[4];
#pragma unroll
  for (int q = 0; q < 4; ++q) {
    int c = tid + 256 * q;
    int row = c >> 3;
    int ucol = (c & 7) ^ (row & 7);
    cc[q] = c;
    goff[q] = (size_t)row * lda + ucol * 8;
  }

  float4v acc[4][4];
#pragma unroll
  for (int i = 0; i < 4; ++i)
#pragma unroll
    for (int j = 0; j < 4; ++j)
      acc[i][j] = (float4v){0.f, 0.f, 0.f, 0.f};

  auto stage = [&](int buf, int k0) {
#pragma unroll
    for (int q = 0; q < 4; ++q)
      gload_lds16(Abase + goff[q] + k0, &As[buf][0][0] + cc[q] * 8);
#pragma unroll
    for (int q = 0; q < 4; ++q)
      gload_lds16(Bbase + goff[q] + k0, &Bs[buf][0][0] + cc[q] * 8);
  };
  auto compute = [&](int b) {
#pragma unroll
    for (int kk = 0; kk < 2; ++kk) {
      bf16x8 af[4], bfr[4];
#pragma unroll
      for (int i = 0; i < 4; ++i)
        af[i]  = ld_frag8(&As[b][wm + i * 16 + lrow][(((kk << 2) + lq) ^ r7) << 3]);
#pragma unroll
      for (int j = 0; j < 4; ++j)
        bfr[j] = ld_frag8(&Bs[b][wn + j * 16 + lrow][(((kk << 2) + lq) ^ r7) << 3]);
#pragma unroll
      for (int i = 0; i < 4; ++i)
#pragma unroll
        for (int j = 0; j < 4; ++j)
          acc[i][j] = __builtin_amdgcn_mfma_f32_16x16x32_bf16(af[i], bfr[j], acc[i][j], 0, 0, 0);
    }
  };

  if constexpr (ONE_SHOT) {
    // klen == 128: both stages in flight, one barrier, no further syncs
    stage(0, 0);
    stage(1, 64);
    __syncthreads();
    compute(0);
    compute(1);
  } else {
    const int NKT = klen / 64;
    stage(0, 0);
    for (int t = 0; t < NKT; ++t) {
      __syncthreads();                     // drains this iter's buffer (vmcnt) + prev compute (lgkm)
      if (t + 1 < NKT) stage((t + 1) & 1, (t + 1) * 64);
      compute(t & 1);
    }
  }

  // block-uniform secondary-output test (DF and QCP are multiples of 128)
  const bool is2nd = (OUT_MODE == 3 && n0 >= DF) || (OUT_MODE == 4 && n0 >= QCP);
  const bool do_bn = BN_STATS && !is2nd;

  float* cs  = (float*)&As[0][0][0];
  float* cs2 = cs + 128;
  if (do_bn) {
    __syncthreads();
    if (tid < 256) cs[tid] = 0.f;          // zero cs[0..127], cs2[0..127]
    __syncthreads();
  }

  float*          outf  = (float*)Cout          + (size_t)z * NB * ldc;
  unsigned short* outh  = (unsigned short*)Cout + (size_t)z * NB * ldc;
  float*          outf2 = (float*)Cout2;

#pragma unroll
  for (int j = 0; j < 4; ++j) {
    int gcol = n0 + wn + j * 16 + lrow;
    float bv = 0.f;
    if (OUT_MODE == 3) {
      if (!is2nd) bv = bias[gcol];
      else if (gcol - DF < NCLS) bv = bias2[gcol - DF];
    } else if (HAS_BIAS && gcol < n_store) bv = bias[gcol];
    float sj = 0.f, s2j = 0.f;
#pragma unroll
    for (int i = 0; i < 4; ++i) {
#pragma unroll
      for (int r = 0; r < 4; ++r) {
        int grow = m0 + wm + i * 16 + lq * 4 + r;  // C/D: col=lane&15, row=(lane>>4)*4+r
        float val = acc[i][j][r] + bv;
        if (do_bn) { sj += val; s2j += val * val; }
        if (OUT_MODE == 0) {
          if (gcol < n_store) outf[(size_t)grow * ldc + gcol] = val;
        } else if (OUT_MODE == 1) {
          if (gcol < n_store) outh[(size_t)grow * ldc + gcol] = f2bf(val);
        } else if (OUT_MODE == 3) {
          if (!is2nd) outh[(size_t)grow * DF + gcol] = f2bf(val);
          else if (gcol - DF < NCLS) outf2[(size_t)grow * NCLS + (gcol - DF)] = val;
        } else if (OUT_MODE == 4) {
          if (!is2nd) { if (gcol < QC) outh[(size_t)grow * QC + gcol] = f2bf(val); }
          else {
            int gc2 = gcol - QCP;
            if (gc2 != grow) outf2[(size_t)grow * CONW + gc2 - (gc2 > grow)] = val;
          }
        }
      }
    }
    if (do_bn) {
      atomicAdd(&cs [wn + j * 16 + lrow], sj);
      atomicAdd(&cs2[wn + j * 16 + lrow], s2j);
    }
  }
  if (do_bn) {
    __syncthreads();
    if (tid < 128) {
      ps [(size_t)blockIdx.y * DF + n0 + tid] = cs[tid];
      ps2[(size_t)blockIdx.y * DF + n0 + tid] = cs2[tid];
    }
  }
}

// ---------------- BatchNorm finish ----------------
__global__ void bn_finish_kernel(const float* __restrict__ ps, const float* __restrict__ ps2,
                                 const float* __restrict__ gamma, const float* __restrict__ beta,
                                 float* __restrict__ scale, float* __restrict__ bias) {
  int j = blockIdx.x * 256 + threadIdx.x;
  float s = 0.f, s2 = 0.f;
  for (int b = 0; b < 16; ++b) { s += ps[b * DF + j]; s2 += ps2[b * DF + j]; }
  float mu  = s  * (1.f / NB);
  float var = s2 * (1.f / NB) - mu * mu;
  float sc = gamma[j] * rsqrtf(var + 1e-5f);
  scale[j] = sc;
  bias[j]  = beta[j] - mu * sc;
}

// bf16 in -> scale/shift/relu -> bf16 out, 8 elems/thread
__global__ void bn_apply_kernel(const unsigned short* __restrict__ h, const float* __restrict__ scale,
                                const float* __restrict__ bias, unsigned short* __restrict__ hb) {
  int base = (blockIdx.x * 256 + threadIdx.x) * 8;
  int j = base & (DF - 1);
  uint4 u = *(const uint4*)(h + base);
  unsigned int uu[4] = {u.x, u.y, u.z, u.w};
  unsigned int rr[4];
#pragma unroll
  for (int e = 0; e < 4; ++e) {
    int col = j + 2 * e;
    float lo = bf2f((unsigned short)(uu[e] & 0xffffu));
    float hi = bf2f((unsigned short)(uu[e] >> 16));
    lo = fmaxf(lo * scale[col] + bias[col], 0.f);
    hi = fmaxf(hi * scale[col + 1] + bias[col + 1], 0.f);
    rr[e] = (unsigned int)f2bf(lo) | ((unsigned int)f2bf(hi) << 16);
  }
  uint4 o; o.x = rr[0]; o.y = rr[1]; o.z = rr[2]; o.w = rr[3];
  *(uint4*)(hb + base) = o;
}

// ---------------- feat: split-K reduce + bias + row-normalize ----------------
__global__ void feat_reduce_norm_kernel(const float* __restrict__ part, const float* __restrict__ b2,
                                        float* __restrict__ fo, unsigned short* __restrict__ fb) {
  int row = blockIdx.x, t = threadIdx.x;   // 64 threads
  float v0 = b2[t], v1 = b2[64 + t];
#pragma unroll
  for (int s = 0; s < FSPLIT; ++s) {
    const float* p = part + (size_t)s * NB * DM + (size_t)row * DM;
    v0 += p[t]; v1 += p[64 + t];
  }
  float ss = v0 * v0 + v1 * v1;
#pragma unroll
  for (int o = 32; o > 0; o >>= 1) ss += __shfl_xor(ss, o);
  float inv = rsqrtf(ss);
  v0 *= inv; v1 *= inv;
  fo[row * DM + t] = v0;       fo[row * DM + 64 + t] = v1;
  fb[row * DM + t] = f2bf(v0); fb[row * DM + 64 + t] = f2bf(v1);
}

// ---------------- top-k (counting sort) + fused labels_con ----------------
// Histogram stored ROTATED-per-thread (hist_addr): scan reads chunk (j+t)&7 at
// static register index j -> banks balanced AND no runtime register indexing
// (r8: runtime cnt[4r] went to scratch, +63us; r7: unrotated = 7.46M conflicts).
__global__ __launch_bounds__(256) void topk_kernel(const unsigned short* __restrict__ sim_qb,
                                                   const int* __restrict__ labels,
                                                   float* __restrict__ out_simcon,
                                                   float* __restrict__ out_labcon) {
  __shared__ unsigned int hist[NBUCK];    // 32 KB; becomes offsets after scan
  __shared__ float sbuf[1024];
  __shared__ unsigned int wtot[4];
  __shared__ int s_tb;

  const int row = blockIdx.x;
  const int c = labels[row];
  const int t = threadIdx.x;
  const int w = t >> 6, lane = t & 63;

  uint4* h4 = (uint4*)hist;
  uint4 z4; z4.x = z4.y = z4.z = z4.w = 0u;
#pragma unroll
  for (int i = 0; i < 8; ++i) h4[t + 256 * i] = z4;

  float vals[32];
  float pvals[QQ];
  const unsigned short* rp = sim_qb + (size_t)row * QC;
#pragma unroll
  for (int j = 0; j < 4; ++j) {
    const int cls = j * 256 + t;
    uint4 u4 = *(const uint4*)(rp + j * 2048 + t * 8);
    const unsigned int uu[4] = {u4.x, u4.y, u4.z, u4.w};
    const bool masked = (cls >= NCLS) || (cls == c);
#pragma unroll
    for (int e = 0; e < 4; ++e) {
      float lo = bf2f((unsigned short)(uu[e] & 0xffffu));
      float hi = bf2f((unsigned short)(uu[e] >> 16));
      if (cls == c) { pvals[2 * e] = lo; pvals[2 * e + 1] = hi; }
      vals[j * 8 + 2 * e]     = masked ? -4.f : lo;
      vals[j * 8 + 2 * e + 1] = masked ? -4.f : hi;
    }
  }
  __syncthreads();

#pragma unroll
  for (int i = 0; i < 32; ++i) {
    float v = vals[i];
    if (v > -3.f) {
      int b = (int)((v + 1.0f) * 4096.0f);
      b = min(max(b, 0), NBUCK - 1);
      atomicAdd(&hist[hist_addr(b)], 1u);
    }
  }
  __syncthreads();

  unsigned int cnt[32];
#pragma unroll
  for (int j = 0; j < 8; ++j) {
    uint4 u = h4[t * 8 + ((j + t) & 7)];   // rotated address, STATIC register index
    cnt[4 * j] = u.x; cnt[4 * j + 1] = u.y; cnt[4 * j + 2] = u.z; cnt[4 * j + 3] = u.w;
  }
  unsigned int chunktot = 0;
#pragma unroll
  for (int i = 0; i < 32; ++i) chunktot += cnt[i];

  unsigned int s = chunktot;
#pragma unroll
  for (int off = 1; off < 64; off <<= 1) {
    unsigned int v = __shfl_down(s, off);
    if (lane + off < 64) s += v;
  }
  if (lane == 0) wtot[w] = s;
  __syncthreads();
  unsigned int wsfx = 0;
#pragma unroll
  for (int ww = 0; ww < 4; ++ww) if (ww > w) wsfx += wtot[ww];
  unsigned int S = wsfx + s - chunktot;

  unsigned int ofsv[32];
#pragma unroll
  for (int i = 31; i >= 0; --i) {
    unsigned int cb = cnt[i];
    ofsv[i] = S;
    unsigned int Sincl = S + cb;
    if (S < 1024u && Sincl >= 1024u) s_tb = t * 32 + i;
    S = Sincl;
  }
#pragma unroll
  for (int j = 0; j < 8; ++j) {
    uint4 u;
    u.x = ofsv[4 * j]; u.y = ofsv[4 * j + 1]; u.z = ofsv[4 * j + 2]; u.w = ofsv[4 * j + 3];
    h4[t * 8 + ((j + t) & 7)] = u;         // rotated address, STATIC register index
  }
  __syncthreads();

  const int tb = s_tb;
#pragma unroll
  for (int i = 0; i < 32; ++i) {
    float v = vals[i];
    if (v > -3.f) {
      int b = (int)((v + 1.0f) * 4096.0f);
      b = min(max(b, 0), NBUCK - 1);
      if (b >= tb) {
        unsigned int p = atomicAdd(&hist[hist_addr(b)], 1u);
        if (p < 1024u) sbuf[p] = v;
      }
    }
  }
  __syncthreads();

  float* orow = out_simcon + (size_t)row * CONW;
  for (int idx = t; idx < 1024; idx += 256) orow[2051 + idx] = sbuf[idx];
  if (t == (c & 255) && (c >> 8) < 4 && (c >> 8) * 256 + t == c) {
    for (int a2 = 1; a2 < QQ; ++a2) {
      float key = pvals[a2]; int b2 = a2 - 1;
      while (b2 >= 0 && pvals[b2] > key) { pvals[b2 + 1] = pvals[b2]; --b2; }
      pvals[b2 + 1] = key;
    }
#pragma unroll
    for (int s2 = 0; s2 < 4; ++s2) orow[2047 + s2] = pvals[s2];
  }

  // fused labels_con (same grid, independent of the topk output above)
  float* lrow = out_labcon + (size_t)row * CONW;
  for (int j = t; j < CONW; j += 256) {
    float v;
    if (j < NB - 1)      v = (labels[j + (j >= row)] == c) ? 1.f : 0.f;
    else if (j < NB + 3) v = 1.f;    // 2047..2050 -> pos ones
    else                 v = 0.f;    // negs
    lrow[j] = v;
  }
}

// ---------------- queue update: fused scan (wave 0) + gather-write (all threads) ----------------
__global__ void queue_update_kernel(const int* __restrict__ labels, const int* __restrict__ qptr_in,
                                    const float* __restrict__ feat, const float* __restrict__ qin,
                                    float* __restrict__ qout, float* __restrict__ qptr_out) {
  __shared__ int wloc[QQ];
  const int c = blockIdx.x;
  const int t = threadIdx.x;         // 256 threads
  const int lane = t & 63;
  if (t < QQ) wloc[t] = -1;
  __syncthreads();
  const int p0 = qptr_in[c];
  if (t < 64) {                      // wave 0 only: ballot scan over first NB/2 labels
    int cnt = 0;
#pragma unroll
    for (int it = 0; it < (NB / 2) / 64; ++it) {
      int i = it * 64 + lane;
      bool pred = (labels[i] == c);
      unsigned long long mask = __ballot(pred);
      if (pred) {
        int rank = __popcll(mask & ((1ull << lane) - 1ull));
        int slot = (p0 + cnt + rank) & (QQ - 1);
        atomicMax(&wloc[slot], i);
      }
      cnt += __popcll(mask);
    }
    if (lane == 0) qptr_out[c] = (float)((p0 + cnt) & (QQ - 1));
  }
  __syncthreads();
  // write the 8 columns owned by class c: cols c*8 .. c*8+7, all 128 d-rows.
  // thread t -> d = t>>1, half = t&1 (4 consecutive cols as float4)
  const int d = t >> 1, half = t & 1;
  const size_t rowbase = (size_t)d * QC + c * QQ + half * 4;
  float4 v = *(const float4*)(qin + rowbase);
  float vv[4] = {v.x, v.y, v.z, v.w};
#pragma unroll
  for (int s = 0; s < 4; ++s) {
    int wsrc = wloc[half * 4 + s];
    if (wsrc >= 0) vv[s] = feat[(size_t)wsrc * DM + d];
  }
  float4 o; o.x = vv[0]; o.y = vv[1]; o.z = vv[2]; o.w = vv[3];
  *(float4*)(qout + rowbase) = o;
}

// ---------------- launcher ----------------
extern "C" void kernel_launch(void* const* d_in, const int* in_sizes, int n_in,
                              void* d_out, int out_size, void* d_ws, size_t ws_size,
                              hipStream_t stream) {
  const float* img     = (const float*)d_in[0];
  const int*   labels  = (const int*)  d_in[1];
  const float* queue_l = (const float*)d_in[2];
  const int*   queue_p = (const int*)  d_in[3];
  // d_in[4] pos_index, d_in[5] neg_index: analytic, unused
  const float* enc_W   = (const float*)d_in[6];
  const float* enc_b   = (const float*)d_in[7];
  const float* W1      = (const float*)d_in[8];
  const float* b1      = (const float*)d_in[9];
  const float* gamma   = (const float*)d_in[10];
  const float* beta    = (const float*)d_in[11];
  const float* W2      = (const float*)d_in[12];
  const float* b2      = (const float*)d_in[13];
  const float* linW    = (const float*)d_in[14];
  const float* linb    = (const float*)d_in[15];

  float* out        = (float*)d_out;
  float* out_simcon = out;
  float* out_labcon = out + (size_t)NB * CONW;
  float* out_logit  = out + (size_t)2 * NB * CONW;
  float* out_qlist  = out_logit + (size_t)NB * NCLS;
  float* out_qptr   = out_qlist + (size_t)DM * QC;

  char* wsp = (char*)d_ws;
  size_t off = 0;
  auto alloc = [&](size_t bytes) -> void* {
    void* p = wsp + off;
    off += (bytes + 255) & ~(size_t)255;
    return p;
  };
  unsigned short* img_bf  = (unsigned short*)alloc((size_t)NB * DIN * 2);
  unsigned short* encWt   = (unsigned short*)alloc((size_t)DF * DIN * 2);   // 2048 x 1024
  // W1t + linWt contiguous (both sizes multiple of 256B) -> fused h+logit B
  unsigned short* W1t     = (unsigned short*)alloc((size_t)DF * DF * 2);    // 2048 x 2048
  unsigned short* linWt   = (unsigned short*)alloc((size_t)NLP * DF * 2);   // 1024 x 2048
  unsigned short* W2t     = (unsigned short*)alloc((size_t)DM * DF * 2);    // 128 x 2048
  // qlt + feat_bf contiguous (qlt size multiple of 256B) -> fused sim B
  unsigned short* qlt     = (unsigned short*)alloc((size_t)QCP * DM * 2);   // 8064 x 128
  unsigned short* feat_bf = (unsigned short*)alloc((size_t)NB * DM * 2);    // 2048 x 128
  unsigned short* mid_bf  = (unsigned short*)alloc((size_t)NB * DF * 2);
  unsigned short* h_pbf   = (unsigned short*)alloc((size_t)NB * DF * 2);    // pre-BN h, bf16
  unsigned short* h_bf    = (unsigned short*)alloc((size_t)NB * DF * 2);    // post-BN h, bf16
  float*          part_s  = (float*)alloc((size_t)16 * DF * 4);
  float*          part_s2 = (float*)alloc((size_t)16 * DF * 4);
  float*          bn_sc   = (float*)alloc((size_t)DF * 4);
  float*          bn_bi   = (float*)alloc((size_t)DF * 4);
  float*          feat_part=(float*)alloc((size_t)FSPLIT * NB * DM * 4);    // 8 MB
  float*          feat_f  = (float*)alloc((size_t)NB * DM * 4);
  unsigned short* sim_qb  = (unsigned short*)alloc((size_t)NB * QC * 2 + 512); // bf16 + read pad

  dim3 blk256(256);
  dim3 tblk(32, 8);

  // --- prep: img conv + transpose of all 5 weight matrices ---
  TDescs td;
  td.src[0] = enc_W;  td.dst[0] = encWt; td.K[0] = DIN; td.N[0] = DF;   td.nx[0] = DF / 32;   td.ky[0] = DIN / 32;
  td.src[1] = W1;     td.dst[1] = W1t;   td.K[1] = DF;  td.N[1] = DF;   td.nx[1] = DF / 32;   td.ky[1] = DF / 32;
  td.src[2] = W2;     td.dst[2] = W2t;   td.K[2] = DF;  td.N[2] = DM;   td.nx[2] = DM / 32;   td.ky[2] = DF / 32;
  td.src[3] = linW;   td.dst[3] = linWt; td.K[3] = DF;  td.N[3] = NCLS; td.nx[3] = NLP / 32;  td.ky[3] = DF / 32;
  td.src[4] = queue_l;td.dst[4] = qlt;   td.K[4] = DM;  td.N[4] = QC;   td.nx[4] = QCP / 32;  td.ky[4] = DM / 32;
  td.src[5] = img;    td.dst[5] = img_bf;td.K[5] = 0;   td.N[5] = 0;    td.nx[5] = 1;         td.ky[5] = 0;
  prep_kernel<<<dim3(4096, 6), tblk, 0, stream>>>(td);

  // --- mid = img @ enc_W + enc_b  (bf16 out) ---
  gemm_bt_kernel<1, true, false, false><<<dim3(DF / 128, NB / 128), blk256, 0, stream>>>(
      img_bf, encWt, enc_b, nullptr, mid_bf, nullptr, DIN, DIN, DF, DF, nullptr, nullptr);

  // --- fused: h_pbf = mid @ W1 + b1 (bf16 + BN stats) ; logit = mid @ lin_W + lin_b ---
  gemm_bt_kernel<3, true, true, false><<<dim3((DF + NLP) / 128, NB / 128), blk256, 0, stream>>>(
      mid_bf, W1t, b1, linb, h_pbf, out_logit, DF, DF, DF, DF, part_s, part_s2);

  // --- batchnorm finish + apply -> h_bf ---
  bn_finish_kernel<<<dim3(DF / 256), blk256, 0, stream>>>(part_s, part_s2, gamma, beta, bn_sc, bn_bi);
  bn_apply_kernel<<<dim3((NB * DF) / 2048), blk256, 0, stream>>>(h_pbf, bn_sc, bn_bi, h_bf);

  // --- feat partials = h @ W2 (split-K x8, f32) ---
  gemm_bt_kernel<0, false, false, false><<<dim3(DM / 128, NB / 128, FSPLIT), blk256, 0, stream>>>(
      h_bf, W2t, nullptr, nullptr, feat_part, nullptr, DF, DF / FSPLIT, DM, DM, nullptr, nullptr);

  // --- feat reduce + bias + normalize ---
  feat_reduce_norm_kernel<<<dim3(NB), dim3(64), 0, stream>>>(feat_part, b2, feat_f, feat_bf);

  // --- fused: sim_q = feat @ queue (bf16) ; sim_b = feat @ feat^T off-diag into sim_con ---
  // K=128 -> ONE_SHOT single-barrier variant
  gemm_bt_kernel<4, false, false, true><<<dim3((QCP + NB) / 128, NB / 128), blk256, 0, stream>>>(
      feat_bf, qlt, nullptr, nullptr, sim_qb, out_simcon, DM, DM, QC, QC, nullptr, nullptr);

  // --- top-k / pos-sel into sim_con + fused labels_con ---
  topk_kernel<<<dim3(NB), blk256, 0, stream>>>(sim_qb, labels, out_simcon, out_labcon);

  // --- queue update (fused scan + write) ---
  queue_update_kernel<<<dim3(NCLS), blk256, 0, stream>>>(labels, queue_p, feat_f, queue_l,
                                                         out_qlist, out_qptr);
}